// Round 1
// 419.287 us; speedup vs baseline: 1.0177x; 1.0177x over previous
//
#include <hip/hip_runtime.h>
#include <math.h>

#define SEQL 784
#define HIDN 512
#define OUTD 10

typedef float v2 __attribute__((ext_vector_type(2)));

// DPP mov: lanes not selected by row_mask, or with invalid source (bound_ctrl),
// yield 0. Single-use results are foldable into v_{add,fmac}_f32_dpp.
template<int CTRL, int RM>
__device__ __forceinline__ float dpp0(float v) {
    int r = __builtin_amdgcn_update_dpp(0, __builtin_bit_cast(int, v),
                                        CTRL, RM, 0xF, true);
    return __builtin_bit_cast(float, r);
}
__device__ __forceinline__ v2 sp(float v) { v2 r; r.x = v; r.y = v; return r; }
__device__ __forceinline__ v2 vfma(v2 a, v2 b, v2 c) {
    return __builtin_elementwise_fma(a, b, c);   // -> v_pk_fma_f32
}

// M[i][o] = sum_j C1[j][i] * W[j][o]  (512 x 10): logits = h2f @ M + b.
__global__ __launch_bounds__(256) void compute_M(const float* __restrict__ C1,
                                                 const float* __restrict__ W,
                                                 float* __restrict__ M) {
    __shared__ float Ws[HIDN * OUTD];
    __shared__ float red[4][64][OUTD];
    const int lane = threadIdx.x & 63, w = threadIdx.x >> 6;
    const int i = blockIdx.x * 64 + lane;
    for (int idx = threadIdx.x; idx < HIDN * OUTD; idx += 256) Ws[idx] = W[idx];
    __syncthreads();
    float acc[OUTD];
#pragma unroll
    for (int o = 0; o < OUTD; ++o) acc[o] = 0.f;
    for (int j = w * 128; j < w * 128 + 128; ++j) {
        float cv = C1[j * HIDN + i];
#pragma unroll
        for (int o = 0; o < OUTD; ++o) acc[o] = fmaf(cv, Ws[j * OUTD + o], acc[o]);
    }
#pragma unroll
    for (int o = 0; o < OUTD; ++o) red[w][lane][o] = acc[o];
    __syncthreads();
    if (w == 0) {
#pragma unroll
        for (int o = 0; o < OUTD; ++o)
            M[i * OUTD + o] = (red[0][lane][o] + red[1][lane][o]) +
                              (red[2][lane][o] + red[3][lane][o]);
    }
}

// One wave per batch row; lane owns 8 hidden elems; layers 1/2 ride in .x/.y
// of packed fp32, with layer 2 lagging TWO steps (y0 carried in registers).
// Per step: h <- tanh(solve((I+cA)h + du*P)) as ONE affine scan over
// (r = prefix P.h, s = solve state); pass 2 uses 1 - a_i + e_i == 0 so the
// global correction obeys S' = a*S + zz with S0 = ri + si. Pass 2 is
// breadth-first so the exp2 / rcp (quarter-rate) stream without dependency
// bubbles; unroll-4 lets pass1(k+1) fill pass2(k) trans latency.
// Paired reciprocal: the two tanh denominators of a packed pair share one
// v_rcp_f32 via rp = rcp(X*Y); tanh fixup = pk_fma(swap(ep), -2*rp, 1).
__global__ __launch_bounds__(256, 1) void ssm_main(const float* __restrict__ x,
                                                   const float* __restrict__ C0,
                                                   const float* __restrict__ Mmat,
                                                   const float* __restrict__ bias,
                                                   float* __restrict__ out) {
    const int tid = threadIdx.x;
    const int wave = tid >> 6;
    const int lane = tid & 63;
    const int row = blockIdx.x * 4 + wave;

    __shared__ __align__(16) float xs[4][SEQL + 8];   // row stride 792 (16B aligned)

    const float DEL = 1.0f / 784.0f;
    {
        const float4* __restrict__ xv =
            (const float4*)(x + (size_t)blockIdx.x * 4 * SEQL);
#pragma unroll
        for (int it = 0; it < 4; ++it) {
            int idx = tid + it * 256;                 // float4 index, need < 784
            if (idx < SEQL) {
                float4 v = xv[idx];
                int r = idx / (SEQL / 4);
                int c = (idx % (SEQL / 4)) * 4;
                float4 w;
                w.x = DEL * v.x; w.y = DEL * v.y;
                w.z = DEL * v.z; w.w = DEL * v.w;
                *(float4*)&xs[r][c] = w;
            }
        }
    }
    if (tid < 32) xs[tid >> 3][SEQL + (tid & 7)] = 0.f;
    __syncthreads();

    // ---- per-lane constants (fp64 -> fp32, matching reference f64 A_d/B_d)
    const double cd = 1.0 / 1568.0;            // step/2
    const double F = 2.0 * 1.4426950408889634; // 2*log2(e) fold for exp2
    float P[8], Ps[8], a_[8], G2[8], mE2[8], FT[8], C0d[8];
    double apD = 0.0, bpD = 1.0;               // in-lane partial (alpha, beta)
#pragma unroll
    for (int j = 0; j < 8; ++j) {
        int i = lane * 8 + j;
        double Pd = sqrt(1.0 + 2.0 * (double)i);
        double dd = 1.0 + cd * (double)(i + 1);
        double fd = 1.0 / dd;
        double ad = (1.0 - cd * (double)i) * fd;
        double mEd = -cd * Pd * fd;
        double ed = Pd * mEd;                   // -cP^2/d ; note 1 - a + e == 0
        double Gd = (1.0 - cd * (double)(i + 1)) * fd;
        apD = ad * apD + ed;
        bpD = ad * bpD;
        P[j]   = (float)Pd;
        Ps[j]  = (float)(Pd / F);
        a_[j]  = (float)ad;
        G2[j]  = (float)(F * Gd);
        mE2[j] = (float)(F * mEd);
        FT[j]  = (float)(F * Pd * fd);
        C0d[j] = DEL * C0[i];
    }
    // ---- scan-level constants mirroring the DPP segment structure
    float ac[6], bc[6];
    {
        double al = apD, be = bpD;
        int rl = lane & 15;
#pragma unroll
        for (int L = 0; L < 4; ++L) {          // row_shr:1,2,4,8 (row-capped)
            int d = 1 << L;
            ac[L] = (float)al; bc[L] = (float)be;
            double pa = __shfl_up(al, d, 64);
            double pb = __shfl_up(be, d, 64);
            if (rl >= d) { al += be * pa; be *= pb; }
        }
        ac[4] = (float)al; bc[4] = (float)be;  // row_bcast:15 -> rows 1,3
        {
            int src = (lane & 32) + 15;
            double pa = __shfl(al, src, 64);
            double pb = __shfl(be, src, 64);
            if (lane & 16) { al += be * pa; be *= pb; }
        }
        ac[5] = (float)al; bc[5] = (float)be;  // row_bcast:31 -> rows 2,3
        {
            double pa = __shfl(al, 31, 64);
            double pb = __shfl(be, 31, 64);
            if (lane >= 32) { al += be * pa; be *= pb; }
        }
    }

    v2 h[8];
#pragma unroll
    for (int j = 0; j < 8; ++j) h[j] = sp(0.f);

    float y0_d1 = 0.f, y0_d2 = 0.f;  // y0 pipeline regs (layer-2 lag = 2)
    float u1 = xs[wave][0];          // pre-scaled by DEL

#pragma unroll 4
    for (int k = 0; k < SEQL + 2; ++k) {
        float u_next = xs[wave][k + 1];
        v2 du; du.x = u1; du.y = y0_d2;   // y0(k-2): two full iters of slack

        // ---- pass 1: per-lane local (r,s); save in_ and zz per elem
        v2 inn[8], zz[8];
        v2 r = sp(0.f), s = sp(0.f);
#pragma unroll
        for (int j = 0; j < 8; ++j) {
            v2 hj = h[j];
            v2 in_ = vfma(sp(mE2[j]), r, sp(G2[j]) * hj);
            in_ = vfma(sp(FT[j]), du, in_);          // du*P folded into w
            inn[j] = in_;
            v2 z = sp(Ps[j]) * in_;
            zz[j] = z;
            s = vfma(sp(a_[j]), s, z);
            r = vfma(sp(P[j]), hj, r);
        }

        // ---- wave affine scan via DPP (single-use, foldable)
#define LVL(CTRL, RM, L) {                                                   \
        s.x = fmaf(bc[L], dpp0<CTRL, RM>(s.x),                               \
                   fmaf(ac[L], dpp0<CTRL, RM>(r.x), s.x));                   \
        s.y = fmaf(bc[L], dpp0<CTRL, RM>(s.y),                               \
                   fmaf(ac[L], dpp0<CTRL, RM>(r.y), s.y));                   \
        r.x += dpp0<CTRL, RM>(r.x);                                          \
        r.y += dpp0<CTRL, RM>(r.y); }
        LVL(0x111, 0xF, 0)   // row_shr:1
        LVL(0x112, 0xF, 1)   // row_shr:2
        LVL(0x114, 0xF, 2)   // row_shr:4
        LVL(0x118, 0xF, 3)   // row_shr:8
        LVL(0x142, 0xA, 4)   // row_bcast:15 -> rows 1,3
        LVL(0x143, 0xC, 5)   // row_bcast:31 -> rows 2,3
#undef LVL
        v2 ri, si;           // exclusive: state entering this lane (lane0 = 0)
        ri.x = dpp0<0x138, 0xF>(r.x);  ri.y = dpp0<0x138, 0xF>(r.y);
        si.x = dpp0<0x138, 0xF>(s.x);  si.y = dpp0<0x138, 0xF>(s.y);

        // ---- pass 2 (breadth-first): yy, exp2, (+1, pair-product), rcp, tanh
        v2 yy[8], ep[8];
        float pm[8], rp[8];
        {
            v2 S = ri + si;
#pragma unroll
            for (int j = 0; j < 8; ++j) {
                yy[j] = vfma(sp(mE2[j]), S, inn[j]);
                S = vfma(sp(a_[j]), S, zz[j]);
            }
        }
#pragma unroll
        for (int j = 0; j < 8; ++j) {
            ep[j].x = __builtin_amdgcn_exp2f(yy[j].x);
            ep[j].y = __builtin_amdgcn_exp2f(yy[j].y);
        }
#pragma unroll
        for (int j = 0; j < 8; ++j) {
            ep[j] = ep[j] + sp(1.f);
            pm[j] = ep[j].x * ep[j].y;            // shared denominator X*Y
        }
#pragma unroll
        for (int j = 0; j < 8; ++j) rp[j] = __builtin_amdgcn_rcpf(pm[j]);
        float part = 0.f;
#pragma unroll
        for (int j = 0; j < 8; ++j) {
            float m2 = -2.f * rp[j];              // fold tanh's -2 into rp
            v2 sw; sw.x = ep[j].y; sw.y = ep[j].x; // op_sel swap in pk_fma
            v2 hn = vfma(sw, sp(m2), sp(1.f));    // 1 - 2/(1+e) per half
            h[j] = hn;
            part = fmaf(C0d[j], hn.x, part);
        }
        // y0 reduce: 2 iterations of slack before consumption
        part += dpp0<0x111, 0xF>(part);
        part += dpp0<0x112, 0xF>(part);
        part += dpp0<0x114, 0xF>(part);
        part += dpp0<0x118, 0xF>(part);
        part += dpp0<0x142, 0xA>(part);
        part += dpp0<0x143, 0xC>(part);
        y0_d2 = y0_d1;
        y0_d1 = __builtin_bit_cast(float,
                  __builtin_amdgcn_readlane(__builtin_bit_cast(int, part), 63));
        u1 = u_next;
    }

    // ---- epilogue: logits[row] = h2_final @ M + b (M direct from global/L2)
    float acc[OUTD];
#pragma unroll
    for (int o = 0; o < OUTD; ++o) acc[o] = 0.f;
#pragma unroll
    for (int j = 0; j < 8; ++j) {
        float hv = h[j].y;
        int i = lane * 8 + j;
#pragma unroll
        for (int o = 0; o < OUTD; ++o)
            acc[o] = fmaf(hv, Mmat[i * OUTD + o], acc[o]);
    }
#pragma unroll
    for (int o = 0; o < OUTD; ++o) {
#pragma unroll
        for (int d = 32; d; d >>= 1) acc[o] += __shfl_xor(acc[o], d, 64);
    }
    if (lane == 0) {
#pragma unroll
        for (int o = 0; o < OUTD; ++o) out[row * OUTD + o] = acc[o] + bias[o];
    }
}

extern "C" void kernel_launch(void* const* d_in, const int* in_sizes, int n_in,
                              void* d_out, int out_size, void* d_ws, size_t ws_size,
                              hipStream_t stream) {
    const float* x  = (const float*)d_in[0];  // (1024, 784)
    const float* C0 = (const float*)d_in[1];  // (1, 512)
    const float* C1 = (const float*)d_in[2];  // (512, 512)
    const float* W  = (const float*)d_in[3];  // (512, 10)
    const float* b  = (const float*)d_in[4];  // (10,)
    float* M = (float*)d_ws;                  // 512*10 fp32 scratch

    compute_M<<<dim3(8), dim3(256), 0, stream>>>(C1, W, M);
    ssm_main<<<dim3(256), dim3(256), 0, stream>>>(x, C0, M, b, (float*)d_out);
}

// Round 2
// 411.830 us; speedup vs baseline: 1.0361x; 1.0181x over previous
//
#include <hip/hip_runtime.h>
#include <math.h>

#define SEQL 784
#define HIDN 512
#define OUTD 10

typedef float v2 __attribute__((ext_vector_type(2)));

// DPP mov: lanes not selected by row_mask, or with invalid source (bound_ctrl),
// yield 0. Single-use results feeding a TIED VOP2 (v_fmac/v_add) fold into
// v_{add,fmac}_f32_dpp; VOP3 v_fma_f32 cannot take DPP on CDNA, so the scan
// is phrased as two serial fmac-shaped updates per value.
template<int CTRL, int RM>
__device__ __forceinline__ float dpp0(float v) {
    int r = __builtin_amdgcn_update_dpp(0, __builtin_bit_cast(int, v),
                                        CTRL, RM, 0xF, true);
    return __builtin_bit_cast(float, r);
}
__device__ __forceinline__ v2 sp(float v) { v2 r; r.x = v; r.y = v; return r; }
__device__ __forceinline__ v2 vfma(v2 a, v2 b, v2 c) {
    return __builtin_elementwise_fma(a, b, c);   // -> v_pk_fma_f32
}

// M[i][o] = sum_j C1[j][i] * W[j][o]  (512 x 10): logits = h2f @ M + b.
__global__ __launch_bounds__(256) void compute_M(const float* __restrict__ C1,
                                                 const float* __restrict__ W,
                                                 float* __restrict__ M) {
    __shared__ float Ws[HIDN * OUTD];
    __shared__ float red[4][64][OUTD];
    const int lane = threadIdx.x & 63, w = threadIdx.x >> 6;
    const int i = blockIdx.x * 64 + lane;
    for (int idx = threadIdx.x; idx < HIDN * OUTD; idx += 256) Ws[idx] = W[idx];
    __syncthreads();
    float acc[OUTD];
#pragma unroll
    for (int o = 0; o < OUTD; ++o) acc[o] = 0.f;
    for (int j = w * 128; j < w * 128 + 128; ++j) {
        float cv = C1[j * HIDN + i];
#pragma unroll
        for (int o = 0; o < OUTD; ++o) acc[o] = fmaf(cv, Ws[j * OUTD + o], acc[o]);
    }
#pragma unroll
    for (int o = 0; o < OUTD; ++o) red[w][lane][o] = acc[o];
    __syncthreads();
    if (w == 0) {
#pragma unroll
        for (int o = 0; o < OUTD; ++o)
            M[i * OUTD + o] = (red[0][lane][o] + red[1][lane][o]) +
                              (red[2][lane][o] + red[3][lane][o]);
    }
}

// One wave per batch row; lane owns 8 hidden elems; layers 1/2 ride in .x/.y
// of packed fp32, with layer 2 lagging TWO steps (y0 carried in registers).
// Per step: h <- tanh(solve((I+cA)h + du*P)) as ONE affine scan over
// (r = prefix P.h, s = solve state); pass 2 uses 1 - a_i + e_i == 0 so the
// global correction obeys S' = a*S + zz with S0 = ri + si.  The S-chain is
// closed-form'd: S_{j-1} = s_{j-1}^local + S0 * prod_{m<j} a_m, so
// yy_j = K_j*S0 + w_j with constant K_j and w_j computed in pass 1 — all 16
// exp2 inputs depend only on S0 (no 8-deep serial chain feeding the trans
// block).  Paired reciprocal: two tanh denominators share one v_rcp_f32 via
// rp = rcp(X*Y); tanh fixup = pk_fma(swap(ep), -2*rp, 1).
__global__ __launch_bounds__(256, 1) void ssm_main(const float* __restrict__ x,
                                                   const float* __restrict__ C0,
                                                   const float* __restrict__ Mmat,
                                                   const float* __restrict__ bias,
                                                   float* __restrict__ out) {
    const int tid = threadIdx.x;
    const int wave = tid >> 6;
    const int lane = tid & 63;
    const int row = blockIdx.x * 4 + wave;

    __shared__ __align__(16) float xs[4][SEQL + 8];   // row stride 792 (16B aligned)

    const float DEL = 1.0f / 784.0f;
    {
        const float4* __restrict__ xv =
            (const float4*)(x + (size_t)blockIdx.x * 4 * SEQL);
#pragma unroll
        for (int it = 0; it < 4; ++it) {
            int idx = tid + it * 256;                 // float4 index, need < 784
            if (idx < SEQL) {
                float4 v = xv[idx];
                int r = idx / (SEQL / 4);
                int c = (idx % (SEQL / 4)) * 4;
                float4 w;
                w.x = DEL * v.x; w.y = DEL * v.y;
                w.z = DEL * v.z; w.w = DEL * v.w;
                *(float4*)&xs[r][c] = w;
            }
        }
    }
    if (tid < 32) xs[tid >> 3][SEQL + (tid & 7)] = 0.f;
    __syncthreads();

    // ---- per-lane constants (fp64 -> fp32, matching reference f64 A_d/B_d)
    const double cd = 1.0 / 1568.0;            // step/2
    const double F = 2.0 * 1.4426950408889634; // 2*log2(e) fold for exp2
    float P[8], Ps[8], a_[8], G2[8], mE2[8], FT[8], C0d[8], K_[8];
    double apD = 0.0, bpD = 1.0;               // in-lane partial (alpha, beta)
    double Aprod = 1.0;                        // prod of a_m, m < j
#pragma unroll
    for (int j = 0; j < 8; ++j) {
        int i = lane * 8 + j;
        double Pd = sqrt(1.0 + 2.0 * (double)i);
        double dd = 1.0 + cd * (double)(i + 1);
        double fd = 1.0 / dd;
        double ad = (1.0 - cd * (double)i) * fd;
        double mEd = -cd * Pd * fd;
        double ed = Pd * mEd;                   // -cP^2/d ; note 1 - a + e == 0
        double Gd = (1.0 - cd * (double)(i + 1)) * fd;
        apD = ad * apD + ed;
        bpD = ad * bpD;
        P[j]   = (float)Pd;
        Ps[j]  = (float)(Pd / F);
        a_[j]  = (float)ad;
        G2[j]  = (float)(F * Gd);
        mE2[j] = (float)(F * mEd);
        FT[j]  = (float)(F * Pd * fd);
        K_[j]  = (float)(F * mEd * Aprod);      // mE2_j * prod_{m<j} a_m
        Aprod *= ad;
        C0d[j] = DEL * C0[i];
    }
    // ---- scan-level constants mirroring the DPP segment structure
    float ac[6], bc[6];
    {
        double al = apD, be = bpD;
        int rl = lane & 15;
#pragma unroll
        for (int L = 0; L < 4; ++L) {          // row_shr:1,2,4,8 (row-capped)
            int d = 1 << L;
            ac[L] = (float)al; bc[L] = (float)be;
            double pa = __shfl_up(al, d, 64);
            double pb = __shfl_up(be, d, 64);
            if (rl >= d) { al += be * pa; be *= pb; }
        }
        ac[4] = (float)al; bc[4] = (float)be;  // row_bcast:15 -> rows 1,3
        {
            int src = (lane & 32) + 15;
            double pa = __shfl(al, src, 64);
            double pb = __shfl(be, src, 64);
            if (lane & 16) { al += be * pa; be *= pb; }
        }
        ac[5] = (float)al; bc[5] = (float)be;  // row_bcast:31 -> rows 2,3
        {
            double pa = __shfl(al, 31, 64);
            double pb = __shfl(be, 31, 64);
            if (lane >= 32) { al += be * pa; be *= pb; }
        }
    }

    v2 h[8];
#pragma unroll
    for (int j = 0; j < 8; ++j) h[j] = sp(0.f);

    float y0_d1 = 0.f, y0_d2 = 0.f;  // y0 pipeline regs (layer-2 lag = 2)
    float u1 = xs[wave][0];          // pre-scaled by DEL

#pragma unroll 4
    for (int k = 0; k < SEQL + 2; ++k) {
        float u_next = xs[wave][k + 1];
        v2 du; du.x = u1; du.y = y0_d2;   // y0(k-2): two full iters of slack

        // ---- pass 1: per-lane local (r,s); save w_j = mE2_j*s_{j-1} + in_j
        v2 w8[8];
        v2 r = sp(0.f), s = sp(0.f);
#pragma unroll
        for (int j = 0; j < 8; ++j) {
            v2 hj = h[j];
            v2 in_ = vfma(sp(mE2[j]), r, sp(G2[j]) * hj);
            in_ = vfma(sp(FT[j]), du, in_);          // du*P folded into w
            w8[j] = vfma(sp(mE2[j]), s, in_);        // uses s BEFORE update j
            v2 z = sp(Ps[j]) * in_;
            s = vfma(sp(a_[j]), s, z);
            r = vfma(sp(P[j]), hj, r);
        }

        // ---- wave affine scan via DPP; two tied fmacs per value per level
        // (bc-term first: consumes OLD s; r updated after s so ac-term sees
        //  OLD r).  Each dpp0 is single-use feeding a VOP2 -> folds.
#define LVL(CTRL, RM, L) {                                                   \
        s.x = fmaf(dpp0<CTRL, RM>(s.x), bc[L], s.x);                         \
        s.x = fmaf(dpp0<CTRL, RM>(r.x), ac[L], s.x);                         \
        s.y = fmaf(dpp0<CTRL, RM>(s.y), bc[L], s.y);                         \
        s.y = fmaf(dpp0<CTRL, RM>(r.y), ac[L], s.y);                         \
        r.x += dpp0<CTRL, RM>(r.x);                                          \
        r.y += dpp0<CTRL, RM>(r.y); }
        LVL(0x111, 0xF, 0)   // row_shr:1
        LVL(0x112, 0xF, 1)   // row_shr:2
        LVL(0x114, 0xF, 2)   // row_shr:4
        LVL(0x118, 0xF, 3)   // row_shr:8
        LVL(0x142, 0xA, 4)   // row_bcast:15 -> rows 1,3
        LVL(0x143, 0xC, 5)   // row_bcast:31 -> rows 2,3
#undef LVL
        v2 ri, si;           // exclusive: state entering this lane (lane0 = 0)
        ri.x = dpp0<0x138, 0xF>(r.x);  ri.y = dpp0<0x138, 0xF>(r.y);
        si.x = dpp0<0x138, 0xF>(s.x);  si.y = dpp0<0x138, 0xF>(s.y);

        // ---- pass 2 (breadth-first): yy all-parallel off S0, exp2, rcp, tanh
        v2 yy[8], ep[8];
        float pm[8], rp[8];
        {
            v2 S0 = ri + si;
#pragma unroll
            for (int j = 0; j < 8; ++j)
                yy[j] = vfma(sp(K_[j]), S0, w8[j]);  // independent per j
        }
#pragma unroll
        for (int j = 0; j < 8; ++j) {
            ep[j].x = __builtin_amdgcn_exp2f(yy[j].x);
            ep[j].y = __builtin_amdgcn_exp2f(yy[j].y);
        }
#pragma unroll
        for (int j = 0; j < 8; ++j) {
            ep[j] = ep[j] + sp(1.f);
            pm[j] = ep[j].x * ep[j].y;            // shared denominator X*Y
        }
#pragma unroll
        for (int j = 0; j < 8; ++j) rp[j] = __builtin_amdgcn_rcpf(pm[j]);
        float part = 0.f;
#pragma unroll
        for (int j = 0; j < 8; ++j) {
            float m2 = -2.f * rp[j];              // fold tanh's -2 into rp
            v2 sw; sw.x = ep[j].y; sw.y = ep[j].x; // op_sel swap in pk_fma
            v2 hn = vfma(sw, sp(m2), sp(1.f));    // 1 - 2/(1+e) per half
            h[j] = hn;
            part = fmaf(C0d[j], hn.x, part);
        }
        // y0 reduce: 2 iterations of slack before consumption
        part += dpp0<0x111, 0xF>(part);
        part += dpp0<0x112, 0xF>(part);
        part += dpp0<0x114, 0xF>(part);
        part += dpp0<0x118, 0xF>(part);
        part += dpp0<0x142, 0xA>(part);
        part += dpp0<0x143, 0xC>(part);
        y0_d2 = y0_d1;
        y0_d1 = __builtin_bit_cast(float,
                  __builtin_amdgcn_readlane(__builtin_bit_cast(int, part), 63));
        u1 = u_next;
    }

    // ---- epilogue: logits[row] = h2_final @ M + b (M direct from global/L2)
    float acc[OUTD];
#pragma unroll
    for (int o = 0; o < OUTD; ++o) acc[o] = 0.f;
#pragma unroll
    for (int j = 0; j < 8; ++j) {
        float hv = h[j].y;
        int i = lane * 8 + j;
#pragma unroll
        for (int o = 0; o < OUTD; ++o)
            acc[o] = fmaf(hv, Mmat[i * OUTD + o], acc[o]);
    }
#pragma unroll
    for (int o = 0; o < OUTD; ++o) {
#pragma unroll
        for (int d = 32; d; d >>= 1) acc[o] += __shfl_xor(acc[o], d, 64);
    }
    if (lane == 0) {
#pragma unroll
        for (int o = 0; o < OUTD; ++o) out[row * OUTD + o] = acc[o] + bias[o];
    }
}

extern "C" void kernel_launch(void* const* d_in, const int* in_sizes, int n_in,
                              void* d_out, int out_size, void* d_ws, size_t ws_size,
                              hipStream_t stream) {
    const float* x  = (const float*)d_in[0];  // (1024, 784)
    const float* C0 = (const float*)d_in[1];  // (1, 512)
    const float* C1 = (const float*)d_in[2];  // (512, 512)
    const float* W  = (const float*)d_in[3];  // (512, 10)
    const float* b  = (const float*)d_in[4];  // (10,)
    float* M = (float*)d_ws;                  // 512*10 fp32 scratch

    compute_M<<<dim3(8), dim3(256), 0, stream>>>(C1, W, M);
    ssm_main<<<dim3(256), dim3(256), 0, stream>>>(x, C0, M, b, (float*)d_out);
}

// Round 3
// 411.348 us; speedup vs baseline: 1.0373x; 1.0012x over previous
//
#include <hip/hip_runtime.h>
#include <math.h>

#define SEQL 784
#define HIDN 512
#define OUTD 10

typedef float v2 __attribute__((ext_vector_type(2)));

// DPP mov: lanes not selected by row_mask, or with invalid source (bound_ctrl),
// yield 0. Single-use results feeding a TIED VOP2 (v_fmac/v_add) fold into
// v_{add,fmac}_f32_dpp; VOP3 v_fma_f32 cannot take DPP on CDNA, so the scan
// is phrased as two serial fmac-shaped updates per value.
template<int CTRL, int RM>
__device__ __forceinline__ float dpp0(float v) {
    int r = __builtin_amdgcn_update_dpp(0, __builtin_bit_cast(int, v),
                                        CTRL, RM, 0xF, true);
    return __builtin_bit_cast(float, r);
}
__device__ __forceinline__ v2 sp(float v) { v2 r; r.x = v; r.y = v; return r; }
__device__ __forceinline__ v2 vfma(v2 a, v2 b, v2 c) {
    return __builtin_elementwise_fma(a, b, c);   // -> v_pk_fma_f32
}

// M[i][o] = sum_j C1[j][i] * W[j][o]  (512 x 10): logits = h2f @ M + b.
__global__ __launch_bounds__(256) void compute_M(const float* __restrict__ C1,
                                                 const float* __restrict__ W,
                                                 float* __restrict__ M) {
    __shared__ float Ws[HIDN * OUTD];
    __shared__ float red[4][64][OUTD];
    const int lane = threadIdx.x & 63, w = threadIdx.x >> 6;
    const int i = blockIdx.x * 64 + lane;
    for (int idx = threadIdx.x; idx < HIDN * OUTD; idx += 256) Ws[idx] = W[idx];
    __syncthreads();
    float acc[OUTD];
#pragma unroll
    for (int o = 0; o < OUTD; ++o) acc[o] = 0.f;
    for (int j = w * 128; j < w * 128 + 128; ++j) {
        float cv = C1[j * HIDN + i];
#pragma unroll
        for (int o = 0; o < OUTD; ++o) acc[o] = fmaf(cv, Ws[j * OUTD + o], acc[o]);
    }
#pragma unroll
    for (int o = 0; o < OUTD; ++o) red[w][lane][o] = acc[o];
    __syncthreads();
    if (w == 0) {
#pragma unroll
        for (int o = 0; o < OUTD; ++o)
            M[i * OUTD + o] = (red[0][lane][o] + red[1][lane][o]) +
                              (red[2][lane][o] + red[3][lane][o]);
    }
}

// Wave affine scan via DPP; two tied fmacs per value per level (bc-term
// first: consumes OLD s; r updated after s so ac-term sees OLD r).
#define LVL(CTRL, RM, L) {                                                   \
        s.x = fmaf(dpp0<CTRL, RM>(s.x), bc[L], s.x);                         \
        s.x = fmaf(dpp0<CTRL, RM>(r.x), ac[L], s.x);                         \
        s.y = fmaf(dpp0<CTRL, RM>(s.y), bc[L], s.y);                         \
        s.y = fmaf(dpp0<CTRL, RM>(r.y), ac[L], s.y);                         \
        r.x += dpp0<CTRL, RM>(r.x);                                          \
        r.y += dpp0<CTRL, RM>(r.y); }

// One SSM step. sigma-rescaled local solve (s_j = Pi_j * sigma_j; sigma update
// is ONE fma with Psp = Ps/Pi), w8 coefficient mE2_j*Pi_{j-1} == K_j.
// tanh tail: ep = (E+1)/2; rp = rcp(ep.x*ep.y) = 4/XY; hn = pk_fma(ep,-rp,1)
// gives the component-SWAPPED tanh pair (1 - rp*ep.x = 1 - 2/Y = tanh(arg.y)).
// Callers alternate layout parity instead of swapping back: even steps take
// h=(L1,L2) and store (L2,L1); odd steps take (L2,L1), swap du packing, and
// store (L1,L2). All per-elem constants are splats so pass 1/2 are
// component-agnostic; PSEL picks which half feeds the y0 dot product.
template<int PSEL>
static __device__ __forceinline__ float do_step(
        v2 (&h)[8], v2 du,
        const float (&P)[8], const float (&G2)[8], const float (&mE2)[8],
        const float (&FT)[8], const float (&K_)[8], const float (&Psp)[8],
        const float (&C0d)[8], float PiL,
        const float (&ac)[6], const float (&bc)[6]) {
    // ---- pass 1: per-lane local (r, sigma); j=0 peeled (r = sigma = 0)
    v2 w8[8];
    v2 in0 = vfma(sp(FT[0]), du, sp(G2[0]) * h[0]);
    w8[0] = in0;
    v2 sg = sp(Psp[0]) * in0;
    v2 r  = sp(P[0]) * h[0];
#pragma unroll
    for (int j = 1; j < 8; ++j) {
        v2 hj = h[j];
        v2 in_ = vfma(sp(mE2[j]), r, sp(G2[j]) * hj);
        in_ = vfma(sp(FT[j]), du, in_);
        w8[j] = vfma(sp(K_[j]), sg, in_);        // mE2_j*Pi_{j-1} == K_j
        sg = vfma(sp(Psp[j]), in_, sg);
        r = vfma(sp(P[j]), hj, r);
    }
    v2 s = sp(PiL) * sg;                         // back to true s for the scan

    LVL(0x111, 0xF, 0)   // row_shr:1
    LVL(0x112, 0xF, 1)   // row_shr:2
    LVL(0x114, 0xF, 2)   // row_shr:4
    LVL(0x118, 0xF, 3)   // row_shr:8
    LVL(0x142, 0xA, 4)   // row_bcast:15 -> rows 1,3
    LVL(0x143, 0xC, 5)   // row_bcast:31 -> rows 2,3
    v2 ri, si;           // exclusive: state entering this lane (lane0 = 0)
    ri.x = dpp0<0x138, 0xF>(r.x);  ri.y = dpp0<0x138, 0xF>(r.y);
    si.x = dpp0<0x138, 0xF>(s.x);  si.y = dpp0<0x138, 0xF>(s.y);

    // ---- pass 2 (breadth-first): yy off S0, exp2, half-ep, rcp, tanh
    v2 yy[8], ep[8];
    float pm[8], rp[8];
    {
        v2 S0 = ri + si;
#pragma unroll
        for (int j = 0; j < 8; ++j)
            yy[j] = vfma(sp(K_[j]), S0, w8[j]);  // independent per j
    }
#pragma unroll
    for (int j = 0; j < 8; ++j) {
        v2 E;
        E.x = __builtin_amdgcn_exp2f(yy[j].x);
        E.y = __builtin_amdgcn_exp2f(yy[j].y);
        ep[j] = vfma(E, sp(0.5f), sp(0.5f));     // (E+1)/2
    }
#pragma unroll
    for (int j = 0; j < 8; ++j) pm[j] = ep[j].x * ep[j].y;
#pragma unroll
    for (int j = 0; j < 8; ++j) rp[j] = __builtin_amdgcn_rcpf(pm[j]);
    float part = 0.f;
#pragma unroll
    for (int j = 0; j < 8; ++j) {
        v2 hn = vfma(ep[j], sp(-rp[j]), sp(1.f)); // swapped tanh pair
        h[j] = hn;
        part = fmaf(C0d[j], PSEL ? hn.y : hn.x, part);
    }
    // y0 reduce: 2 iterations of slack before consumption
    part += dpp0<0x111, 0xF>(part);
    part += dpp0<0x112, 0xF>(part);
    part += dpp0<0x114, 0xF>(part);
    part += dpp0<0x118, 0xF>(part);
    part += dpp0<0x142, 0xA>(part);
    part += dpp0<0x143, 0xC>(part);
    return part;
}

// One wave per batch row; lane owns 8 hidden elems; layers 1/2 ride in .x/.y
// of packed fp32 (parity-alternating order), layer 2 lagging TWO steps.
__global__ __launch_bounds__(256, 1) void ssm_main(const float* __restrict__ x,
                                                   const float* __restrict__ C0,
                                                   const float* __restrict__ Mmat,
                                                   const float* __restrict__ bias,
                                                   float* __restrict__ out) {
    const int tid = threadIdx.x;
    const int wave = tid >> 6;
    const int lane = tid & 63;
    const int row = blockIdx.x * 4 + wave;

    __shared__ __align__(16) float xs[4][SEQL + 8];   // row stride 792 (16B aligned)

    const float DEL = 1.0f / 784.0f;
    {
        const float4* __restrict__ xv =
            (const float4*)(x + (size_t)blockIdx.x * 4 * SEQL);
#pragma unroll
        for (int it = 0; it < 4; ++it) {
            int idx = tid + it * 256;                 // float4 index, need < 784
            if (idx < SEQL) {
                float4 v = xv[idx];
                int r = idx / (SEQL / 4);
                int c = (idx % (SEQL / 4)) * 4;
                float4 w;
                w.x = DEL * v.x; w.y = DEL * v.y;
                w.z = DEL * v.z; w.w = DEL * v.w;
                *(float4*)&xs[r][c] = w;
            }
        }
    }
    if (tid < 32) xs[tid >> 3][SEQL + (tid & 7)] = 0.f;
    __syncthreads();

    // ---- per-lane constants (fp64 -> fp32, matching reference f64 A_d/B_d)
    const double cd = 1.0 / 1568.0;            // step/2
    const double F = 2.0 * 1.4426950408889634; // 2*log2(e) fold for exp2
    float P[8], G2[8], mE2[8], FT[8], C0d[8], K_[8], Psp[8], PiL;
    double apD = 0.0, bpD = 1.0;               // in-lane partial (alpha, beta)
    double Aprod = 1.0;                        // prod of a_m, m < j
#pragma unroll
    for (int j = 0; j < 8; ++j) {
        int i = lane * 8 + j;
        double Pd = sqrt(1.0 + 2.0 * (double)i);
        double dd = 1.0 + cd * (double)(i + 1);
        double fd = 1.0 / dd;
        double ad = (1.0 - cd * (double)i) * fd;
        double mEd = -cd * Pd * fd;
        double ed = Pd * mEd;                   // -cP^2/d ; note 1 - a + e == 0
        double Gd = (1.0 - cd * (double)(i + 1)) * fd;
        apD = ad * apD + ed;
        bpD = ad * bpD;
        P[j]   = (float)Pd;
        G2[j]  = (float)(F * Gd);
        mE2[j] = (float)(F * mEd);
        FT[j]  = (float)(F * Pd * fd);
        K_[j]  = (float)(F * mEd * Aprod);      // mE2_j * prod_{m<j} a_m
        Psp[j] = (float)((Pd / F) / (Aprod * ad)); // Ps_j / Pi_j
        Aprod *= ad;
        C0d[j] = DEL * C0[i];
    }
    PiL = (float)Aprod;                         // Pi_7
    // ---- scan-level constants mirroring the DPP segment structure
    float ac[6], bc[6];
    {
        double al = apD, be = bpD;
        int rl = lane & 15;
#pragma unroll
        for (int L = 0; L < 4; ++L) {          // row_shr:1,2,4,8 (row-capped)
            int d = 1 << L;
            ac[L] = (float)al; bc[L] = (float)be;
            double pa = __shfl_up(al, d, 64);
            double pb = __shfl_up(be, d, 64);
            if (rl >= d) { al += be * pa; be *= pb; }
        }
        ac[4] = (float)al; bc[4] = (float)be;  // row_bcast:15 -> rows 1,3
        {
            int src = (lane & 32) + 15;
            double pa = __shfl(al, src, 64);
            double pb = __shfl(be, src, 64);
            if (lane & 16) { al += be * pa; be *= pb; }
        }
        ac[5] = (float)al; bc[5] = (float)be;  // row_bcast:31 -> rows 2,3
        {
            double pa = __shfl(al, 31, 64);
            double pb = __shfl(be, 31, 64);
            if (lane >= 32) { al += be * pa; be *= pb; }
        }
    }

    v2 h[8];
#pragma unroll
    for (int j = 0; j < 8; ++j) h[j] = sp(0.f);

    float y0_d1 = 0.f, y0_d2 = 0.f;  // y0 pipeline regs (layer-2 lag = 2)
    float u1 = xs[wave][0];          // pre-scaled by DEL

#pragma unroll 2
    for (int k = 0; k < SEQL + 2; k += 2) {
        {   // even step: h in (L1,L2) order; produces (L2,L1); y0 from .y
            float u_nx = xs[wave][k + 1];
            v2 du; du.x = u1; du.y = y0_d2;
            float part = do_step<1>(h, du, P, G2, mE2, FT, K_, Psp, C0d, PiL,
                                    ac, bc);
            y0_d2 = y0_d1;
            y0_d1 = __builtin_bit_cast(float,
                      __builtin_amdgcn_readlane(__builtin_bit_cast(int, part), 63));
            u1 = u_nx;
        }
        {   // odd step: h in (L2,L1) order; produces (L1,L2); y0 from .x
            float u_nx = xs[wave][k + 2];
            v2 du; du.x = y0_d2; du.y = u1;
            float part = do_step<0>(h, du, P, G2, mE2, FT, K_, Psp, C0d, PiL,
                                    ac, bc);
            y0_d2 = y0_d1;
            y0_d1 = __builtin_bit_cast(float,
                      __builtin_amdgcn_readlane(__builtin_bit_cast(int, part), 63));
            u1 = u_nx;
        }
    }

    // ---- epilogue: logits[row] = h2_final @ M + b (M direct from global/L2)
    // (total steps 786 is even, so h ends in (L1,L2) order: h.y = layer 2)
    float acc[OUTD];
#pragma unroll
    for (int o = 0; o < OUTD; ++o) acc[o] = 0.f;
#pragma unroll
    for (int j = 0; j < 8; ++j) {
        float hv = h[j].y;
        int i = lane * 8 + j;
#pragma unroll
        for (int o = 0; o < OUTD; ++o)
            acc[o] = fmaf(hv, Mmat[i * OUTD + o], acc[o]);
    }
#pragma unroll
    for (int o = 0; o < OUTD; ++o) {
#pragma unroll
        for (int d = 32; d; d >>= 1) acc[o] += __shfl_xor(acc[o], d, 64);
    }
    if (lane == 0) {
#pragma unroll
        for (int o = 0; o < OUTD; ++o) out[row * OUTD + o] = acc[o] + bias[o];
    }
}

extern "C" void kernel_launch(void* const* d_in, const int* in_sizes, int n_in,
                              void* d_out, int out_size, void* d_ws, size_t ws_size,
                              hipStream_t stream) {
    const float* x  = (const float*)d_in[0];  // (1024, 784)
    const float* C0 = (const float*)d_in[1];  // (1, 512)
    const float* C1 = (const float*)d_in[2];  // (512, 512)
    const float* W  = (const float*)d_in[3];  // (512, 10)
    const float* b  = (const float*)d_in[4];  // (10,)
    float* M = (float*)d_ws;                  // 512*10 fp32 scratch

    compute_M<<<dim3(8), dim3(256), 0, stream>>>(C1, W, M);
    ssm_main<<<dim3(256), dim3(256), 0, stream>>>(x, C0, M, b, (float*)d_out);
}

// Round 4
// 371.444 us; speedup vs baseline: 1.1487x; 1.1074x over previous
//
#include <hip/hip_runtime.h>
#include <math.h>

#define SEQL 784
#define HIDN 512
#define OUTD 10

typedef float v2 __attribute__((ext_vector_type(2)));

// DPP mov: lanes not selected by row_mask, or with invalid source (bound_ctrl),
// yield 0. Single-use results feeding a TIED VOP2 (v_fmac/v_add) fold into
// v_{add,fmac}_f32_dpp; VOP3 v_fma_f32 cannot take DPP on CDNA, so the scan
// is phrased as two serial fmac-shaped updates per value.
template<int CTRL, int RM>
__device__ __forceinline__ float dpp0(float v) {
    int r = __builtin_amdgcn_update_dpp(0, __builtin_bit_cast(int, v),
                                        CTRL, RM, 0xF, true);
    return __builtin_bit_cast(float, r);
}
__device__ __forceinline__ v2 sp(float v) { v2 r; r.x = v; r.y = v; return r; }
__device__ __forceinline__ v2 vfma(v2 a, v2 b, v2 c) {
    return __builtin_elementwise_fma(a, b, c);   // -> v_pk_fma_f32
}

// M[i][o] = sum_j C1[j][i] * W[j][o]  (512 x 10): logits = h2f @ M + b.
__global__ __launch_bounds__(256) void compute_M(const float* __restrict__ C1,
                                                 const float* __restrict__ W,
                                                 float* __restrict__ M) {
    __shared__ float Ws[HIDN * OUTD];
    __shared__ float red[4][64][OUTD];
    const int lane = threadIdx.x & 63, w = threadIdx.x >> 6;
    const int i = blockIdx.x * 64 + lane;
    for (int idx = threadIdx.x; idx < HIDN * OUTD; idx += 256) Ws[idx] = W[idx];
    __syncthreads();
    float acc[OUTD];
#pragma unroll
    for (int o = 0; o < OUTD; ++o) acc[o] = 0.f;
    for (int j = w * 128; j < w * 128 + 128; ++j) {
        float cv = C1[j * HIDN + i];
#pragma unroll
        for (int o = 0; o < OUTD; ++o) acc[o] = fmaf(cv, Ws[j * OUTD + o], acc[o]);
    }
#pragma unroll
    for (int o = 0; o < OUTD; ++o) red[w][lane][o] = acc[o];
    __syncthreads();
    if (w == 0) {
#pragma unroll
        for (int o = 0; o < OUTD; ++o)
            M[i * OUTD + o] = (red[0][lane][o] + red[1][lane][o]) +
                              (red[2][lane][o] + red[3][lane][o]);
    }
}

// Wave affine scan via DPP; two tied fmacs per value per level (bc-term
// first: consumes OLD s; r updated after s so ac-term sees OLD r).
#define LVL(CTRL, RM, L) {                                                   \
        s.x = fmaf(dpp0<CTRL, RM>(s.x), bc[L], s.x);                         \
        s.x = fmaf(dpp0<CTRL, RM>(r.x), ac[L], s.x);                         \
        s.y = fmaf(dpp0<CTRL, RM>(s.y), bc[L], s.y);                         \
        s.y = fmaf(dpp0<CTRL, RM>(r.y), ac[L], s.y);                         \
        r.x += dpp0<CTRL, RM>(r.x);                                          \
        r.y += dpp0<CTRL, RM>(r.y); }

// One SSM step on G2-scaled state H = G2*h.
//  pass1: in_ = mE2*r + H + FT*du (no per-j G2 mul); r advances with P2=P/G2
//  so r keeps its TRUE value (scan constants unchanged).  sigma-rescaled
//  local solve (s = Pi * sg); w8 coeff mE2_j*Pi_{j-1} == K_j.
//  tanh tail: ep=(E+1)/2; rp=rcp(ep.x*ep.y); hn-pair comes out component-
//  SWAPPED; callers alternate layout parity (even: (L1,L2)->(L2,L1), odd
//  swaps du packing and PSEL).  H is regenerated as fma(ep, -G2*rp, G2).
template<int PSEL>
static __device__ __forceinline__ float do_step(
        v2 (&H)[8], v2 du,
        const float (&P2)[8], const float (&G2)[8], const float (&mE2)[8],
        const float (&FT)[8], const float (&K_)[8], const float (&Psp)[8],
        const float (&C0d2)[8], float PiL,
        const float (&ac)[6], const float (&bc)[6]) {
    // ---- pass 1: per-lane local (r, sigma); j=0 peeled (r = sigma = 0)
    v2 w8[8];
    v2 in0 = vfma(sp(FT[0]), du, H[0]);
    w8[0] = in0;
    v2 sg = sp(Psp[0]) * in0;
    v2 r  = sp(P2[0]) * H[0];
#pragma unroll
    for (int j = 1; j < 8; ++j) {
        v2 in_ = vfma(sp(FT[j]), du, vfma(sp(mE2[j]), r, H[j]));
        w8[j] = vfma(sp(K_[j]), sg, in_);        // mE2_j*Pi_{j-1} == K_j
        sg = vfma(sp(Psp[j]), in_, sg);
        r = vfma(sp(P2[j]), H[j], r);
    }
    v2 s = sp(PiL) * sg;                         // back to true s for the scan

    LVL(0x111, 0xF, 0)   // row_shr:1
    LVL(0x112, 0xF, 1)   // row_shr:2
    LVL(0x114, 0xF, 2)   // row_shr:4
    LVL(0x118, 0xF, 3)   // row_shr:8
    LVL(0x142, 0xA, 4)   // row_bcast:15 -> rows 1,3
    LVL(0x143, 0xC, 5)   // row_bcast:31 -> rows 2,3

    // exclusive incoming state: S0 = shift1(r + s)  (lane0 = 0)
    v2 t = r + s, S0;
    S0.x = dpp0<0x138, 0xF>(t.x);  S0.y = dpp0<0x138, 0xF>(t.y);

    // ---- pass 2 (breadth-first): yy off S0, exp2, half-ep, rcp, H-rebuild
    v2 yy[8], ep[8];
    float pm[8], rp[8];
#pragma unroll
    for (int j = 0; j < 8; ++j)
        yy[j] = vfma(sp(K_[j]), S0, w8[j]);      // independent per j
#pragma unroll
    for (int j = 0; j < 8; ++j) {
        v2 E;
        E.x = __builtin_amdgcn_exp2f(yy[j].x);
        E.y = __builtin_amdgcn_exp2f(yy[j].y);
        ep[j] = vfma(E, sp(0.5f), sp(0.5f));     // (E+1)/2
    }
#pragma unroll
    for (int j = 0; j < 8; ++j) pm[j] = ep[j].x * ep[j].y;
#pragma unroll
    for (int j = 0; j < 8; ++j) rp[j] = __builtin_amdgcn_rcpf(pm[j]);
    float part = 0.f;
#pragma unroll
    for (int j = 0; j < 8; ++j) {
        float nt = -G2[j] * rp[j];               // fold G2 into tanh fixup
        v2 hn = vfma(ep[j], sp(nt), sp(G2[j]));  // G2 * swapped tanh pair
        H[j] = hn;
        part = fmaf(C0d2[j], PSEL ? hn.y : hn.x, part);
    }
    // y0 reduce: 2 iterations of slack before consumption
    part += dpp0<0x111, 0xF>(part);
    part += dpp0<0x112, 0xF>(part);
    part += dpp0<0x114, 0xF>(part);
    part += dpp0<0x118, 0xF>(part);
    part += dpp0<0x142, 0xA>(part);
    part += dpp0<0x143, 0xC>(part);
    return part;
}

// One wave per batch row; lane owns 8 hidden elems; layers 1/2 ride in .x/.y
// of packed fp32 (parity-alternating order), layer 2 lagging TWO steps.
__global__ __launch_bounds__(256, 1) void ssm_main(const float* __restrict__ x,
                                                   const float* __restrict__ C0,
                                                   const float* __restrict__ Mmat,
                                                   const float* __restrict__ bias,
                                                   float* __restrict__ out) {
    const int tid = threadIdx.x;
    const int wave = tid >> 6;
    const int lane = tid & 63;
    const int row = blockIdx.x * 4 + wave;

    __shared__ __align__(16) float xs[4][SEQL + 8];   // row stride 792 (16B aligned)

    const float DEL = 1.0f / 784.0f;
    {
        const float4* __restrict__ xv =
            (const float4*)(x + (size_t)blockIdx.x * 4 * SEQL);
#pragma unroll
        for (int it = 0; it < 4; ++it) {
            int idx = tid + it * 256;                 // float4 index, need < 784
            if (idx < SEQL) {
                float4 v = xv[idx];
                int r = idx / (SEQL / 4);
                int c = (idx % (SEQL / 4)) * 4;
                float4 w;
                w.x = DEL * v.x; w.y = DEL * v.y;
                w.z = DEL * v.z; w.w = DEL * v.w;
                *(float4*)&xs[r][c] = w;
            }
        }
    }
    if (tid < 32) xs[tid >> 3][SEQL + (tid & 7)] = 0.f;
    __syncthreads();

    // ---- per-lane constants (fp64 -> fp32, matching reference f64 A_d/B_d)
    const double cd = 1.0 / 1568.0;            // step/2
    const double F = 2.0 * 1.4426950408889634; // 2*log2(e) fold for exp2
    float P2[8], G2[8], mE2[8], FT[8], C0d2[8], K_[8], Psp[8], PiL;
    double apD = 0.0, bpD = 1.0;               // in-lane partial (alpha, beta)
    double Aprod = 1.0;                        // prod of a_m, m < j
#pragma unroll
    for (int j = 0; j < 8; ++j) {
        int i = lane * 8 + j;
        double Pd = sqrt(1.0 + 2.0 * (double)i);
        double dd = 1.0 + cd * (double)(i + 1);
        double fd = 1.0 / dd;
        double ad = (1.0 - cd * (double)i) * fd;
        double mEd = -cd * Pd * fd;
        double ed = Pd * mEd;                   // -cP^2/d ; note 1 - a + e == 0
        double Gd = (1.0 - cd * (double)(i + 1)) * fd;
        double G2d = F * Gd;
        apD = ad * apD + ed;
        bpD = ad * bpD;
        P2[j]  = (float)(Pd / G2d);             // r advances on H = G2*h
        G2[j]  = (float)G2d;
        mE2[j] = (float)(F * mEd);
        FT[j]  = (float)(F * Pd * fd);
        K_[j]  = (float)(F * mEd * Aprod);      // mE2_j * prod_{m<j} a_m
        Psp[j] = (float)((Pd / F) / (Aprod * ad)); // Ps_j / Pi_j
        Aprod *= ad;
        C0d2[j] = (float)((double)DEL * (double)C0[i] / G2d);
    }
    PiL = (float)Aprod;                         // Pi_7
    // ---- scan-level constants mirroring the DPP segment structure
    float ac[6], bc[6];
    {
        double al = apD, be = bpD;
        int rl = lane & 15;
#pragma unroll
        for (int L = 0; L < 4; ++L) {          // row_shr:1,2,4,8 (row-capped)
            int d = 1 << L;
            ac[L] = (float)al; bc[L] = (float)be;
            double pa = __shfl_up(al, d, 64);
            double pb = __shfl_up(be, d, 64);
            if (rl >= d) { al += be * pa; be *= pb; }
        }
        ac[4] = (float)al; bc[4] = (float)be;  // row_bcast:15 -> rows 1,3
        {
            int src = (lane & 32) + 15;
            double pa = __shfl(al, src, 64);
            double pb = __shfl(be, src, 64);
            if (lane & 16) { al += be * pa; be *= pb; }
        }
        ac[5] = (float)al; bc[5] = (float)be;  // row_bcast:31 -> rows 2,3
        {
            double pa = __shfl(al, 31, 64);
            double pb = __shfl(be, 31, 64);
            if (lane >= 32) { al += be * pa; be *= pb; }
        }
    }

    v2 H[8];
#pragma unroll
    for (int j = 0; j < 8; ++j) H[j] = sp(0.f);

    float y0_d1 = 0.f, y0_d2 = 0.f;  // y0 pipeline regs (layer-2 lag = 2)
    float u1 = xs[wave][0];          // pre-scaled by DEL

#pragma unroll 4
    for (int k = 0; k < SEQL + 2; k += 2) {
        {   // even step: H in (L1,L2) order; produces (L2,L1); y0 from .y
            float u_nx = xs[wave][k + 1];
            v2 du; du.x = u1; du.y = y0_d2;
            float part = do_step<1>(H, du, P2, G2, mE2, FT, K_, Psp, C0d2, PiL,
                                    ac, bc);
            y0_d2 = y0_d1;
            y0_d1 = __builtin_bit_cast(float,
                      __builtin_amdgcn_readlane(__builtin_bit_cast(int, part), 63));
            u1 = u_nx;
        }
        {   // odd step: H in (L2,L1) order; produces (L1,L2); y0 from .x
            float u_nx = xs[wave][k + 2];
            v2 du; du.x = y0_d2; du.y = u1;
            float part = do_step<0>(H, du, P2, G2, mE2, FT, K_, Psp, C0d2, PiL,
                                    ac, bc);
            y0_d2 = y0_d1;
            y0_d1 = __builtin_bit_cast(float,
                      __builtin_amdgcn_readlane(__builtin_bit_cast(int, part), 63));
            u1 = u_nx;
        }
    }

    // ---- epilogue: logits[row] = h2_final @ M + b (M direct from global/L2)
    // (total steps 786 is even, so H ends in (L1,L2) order: H.y = G2*h_layer2)
    float acc[OUTD];
#pragma unroll
    for (int o = 0; o < OUTD; ++o) acc[o] = 0.f;
#pragma unroll
    for (int j = 0; j < 8; ++j) {
        float hv = H[j].y / G2[j];               // one-time unscale
        int i = lane * 8 + j;
#pragma unroll
        for (int o = 0; o < OUTD; ++o)
            acc[o] = fmaf(hv, Mmat[i * OUTD + o], acc[o]);
    }
#pragma unroll
    for (int o = 0; o < OUTD; ++o) {
#pragma unroll
        for (int d = 32; d; d >>= 1) acc[o] += __shfl_xor(acc[o], d, 64);
    }
    if (lane == 0) {
#pragma unroll
        for (int o = 0; o < OUTD; ++o) out[row * OUTD + o] = acc[o] + bias[o];
    }
}

extern "C" void kernel_launch(void* const* d_in, const int* in_sizes, int n_in,
                              void* d_out, int out_size, void* d_ws, size_t ws_size,
                              hipStream_t stream) {
    const float* x  = (const float*)d_in[0];  // (1024, 784)
    const float* C0 = (const float*)d_in[1];  // (1, 512)
    const float* C1 = (const float*)d_in[2];  // (512, 512)
    const float* W  = (const float*)d_in[3];  // (512, 10)
    const float* b  = (const float*)d_in[4];  // (10,)
    float* M = (float*)d_ws;                  // 512*10 fp32 scratch

    compute_M<<<dim3(8), dim3(256), 0, stream>>>(C1, W, M);
    ssm_main<<<dim3(256), dim3(256), 0, stream>>>(x, C0, M, b, (float*)d_out);
}